// Round 2
// baseline (1364.914 us; speedup 1.0000x reference)
//
#include <hip/hip_runtime.h>

#define NSITES 1000000
#define CCH 64
#define EPS_BN 1e-5f

typedef __bf16 bf16x8 __attribute__((ext_vector_type(8)));
typedef float f32x4 __attribute__((ext_vector_type(4)));
typedef unsigned short ushort_t;

__device__ __forceinline__ unsigned short f2bf(float x) {
    __bf16 h = (__bf16)x;
    return __builtin_bit_cast(unsigned short, h);
}
__device__ __forceinline__ float bf2f(unsigned short u) {
    return (float)__builtin_bit_cast(__bf16, u);
}

// ---------------- cast features fp32 -> bf16 ----------------
__global__ void cast_kernel(const float* __restrict__ f, ushort_t* __restrict__ o, int total8) {
    int stride = gridDim.x * blockDim.x;
    for (int i = blockIdx.x * blockDim.x + threadIdx.x; i < total8; i += stride) {
        const float4* fp = (const float4*)(f + (size_t)i * 8);
        float4 v0 = fp[0];
        float4 v1 = fp[1];
        uint4 packed;
        ushort_t* up = (ushort_t*)&packed;
        up[0] = f2bf(v0.x); up[1] = f2bf(v0.y); up[2] = f2bf(v0.z); up[3] = f2bf(v0.w);
        up[4] = f2bf(v1.x); up[5] = f2bf(v1.y); up[6] = f2bf(v1.z); up[7] = f2bf(v1.w);
        *(uint4*)(o + (size_t)i * 8) = packed;
    }
}

// ---------------- swizzle W (fp32 [9][64][64]) into B-fragment order bf16 ----------------
// dst index = (((tap*2+kk)*4 + w)*64 + lane)*8 + j
// maps to W[tap][k = 32*kk + 8*(lane>>4) + j][n = 16*w + (lane&15)]
__global__ void swizzle_kernel(const float* __restrict__ W1, const float* __restrict__ W2,
                               ushort_t* __restrict__ W1s, ushort_t* __restrict__ W2s) {
    int t = blockIdx.x * blockDim.x + threadIdx.x;  // 0..73727
    const float* Wg = W1;
    ushort_t* dst = W1s;
    int u = t;
    if (t >= 36864) { Wg = W2; dst = W2s; u = t - 36864; }
    int j = u & 7;
    int lane = (u >> 3) & 63;
    int w = (u >> 9) & 3;
    int kk = (u >> 11) & 1;
    int tap = u >> 12;
    int k = 32 * kk + 8 * (lane >> 4) + j;
    int n = 16 * w + (lane & 15);
    dst[u] = f2bf(Wg[tap * 4096 + k * 64 + n]);
}

// ---------------- conv kernel: 64 sites x 64 ch per block ----------------
// PRE: apply y = relu(a*x+b) to gathered input (conv2)
// OUT_BF16: write bf16 h1 (conv1) else fp32 (conv2)
template <bool PRE, bool OUT_BF16>
__global__ __launch_bounds__(256) void conv_kernel(
    const ushort_t* __restrict__ fin,   // [N][64] bf16
    const int* __restrict__ nbr,        // [N][9]
    const ushort_t* __restrict__ Wsw,   // swizzled bf16 W fragments
    const float* __restrict__ pre_a, const float* __restrict__ pre_b,
    ushort_t* __restrict__ out_bf, float* __restrict__ out_f,
    float* __restrict__ s_sum, float* __restrict__ s_sq) {

    __shared__ alignas(16) ushort_t Ash[64 * 72];  // 64 rows, stride 72 (2-way bank alias only)

    const int tid  = threadIdx.x;
    const int w    = tid >> 6;      // wave 0..3 -> channel group
    const int lane = tid & 63;
    const int quad = lane >> 4;
    const int l15  = lane & 15;
    const int sBase = blockIdx.x * 64;
    const int sp = tid >> 2;        // staging site 0..63
    const int pp = tid & 3;        // staging part 0..3, each part = 16 channels (32B)

    float a_r[16], b_r[16];
    if constexpr (PRE) {
#pragma unroll
        for (int j = 0; j < 16; ++j) {
            a_r[j] = pre_a[pp * 16 + j];
            b_r[j] = pre_b[pp * 16 + j];
        }
    }

    f32x4 acc[4];
#pragma unroll
    for (int mt = 0; mt < 4; ++mt) acc[mt] = (f32x4){0.f, 0.f, 0.f, 0.f};

#pragma unroll 1
    for (int tap = 0; tap < 9; ++tap) {
        // B fragments for this wave's channel group (L2-hot swizzled W)
        bf16x8 b0 = *(const bf16x8*)(Wsw + (size_t)(((tap * 2 + 0) * 4 + w) * 64 + lane) * 8);
        bf16x8 b1 = *(const bf16x8*)(Wsw + (size_t)(((tap * 2 + 1) * 4 + w) * 64 + lane) * 8);

        // gather: 4 threads per site, each stages 32B (16 channels) => full 128B row
        int idx = nbr[(size_t)(sBase + sp) * 9 + tap];
        uint4 raw0 = make_uint4(0u, 0u, 0u, 0u);
        uint4 raw1 = make_uint4(0u, 0u, 0u, 0u);
        if (idx >= 0) {
            const uint4* src = (const uint4*)(fin + (size_t)idx * 64 + pp * 16);
            raw0 = src[0];
            raw1 = src[1];
            if constexpr (PRE) {
                ushort_t* u0 = (ushort_t*)&raw0;
                ushort_t* u1 = (ushort_t*)&raw1;
#pragma unroll
                for (int j = 0; j < 8; ++j) {
                    float x0 = bf2f(u0[j]);
                    u0[j] = f2bf(fmaxf(a_r[j] * x0 + b_r[j], 0.f));
                    float x1 = bf2f(u1[j]);
                    u1[j] = f2bf(fmaxf(a_r[8 + j] * x1 + b_r[8 + j], 0.f));
                }
            }
        }
        *(uint4*)(&Ash[sp * 72 + pp * 16]) = raw0;
        *(uint4*)(&Ash[sp * 72 + pp * 16 + 8]) = raw1;
        __syncthreads();

#pragma unroll
        for (int mt = 0; mt < 4; ++mt) {
            int site = 16 * mt + l15;
            bf16x8 a0 = *(const bf16x8*)(&Ash[site * 72 + 8 * quad]);
            bf16x8 a1 = *(const bf16x8*)(&Ash[site * 72 + 32 + 8 * quad]);
            acc[mt] = __builtin_amdgcn_mfma_f32_16x16x32_bf16(a0, b0, acc[mt], 0, 0, 0);
            acc[mt] = __builtin_amdgcn_mfma_f32_16x16x32_bf16(a1, b1, acc[mt], 0, 0, 0);
        }
        __syncthreads();
    }

    // epilogue: C/D layout col=lane&15 (channel), row=4*quad+reg (site within 16-tile)
    const int ch = 16 * w + l15;
    float ssum = 0.f, ssq = 0.f;

    if constexpr (OUT_BF16) {
#pragma unroll
        for (int mt = 0; mt < 4; ++mt) {
#pragma unroll
            for (int r = 0; r < 4; ++r) {
                int site = 16 * mt + 4 * quad + r;
                float v = acc[mt][r];
                ssum += v;
                ssq += v * v;
                Ash[site * 72 + ch] = f2bf(v);
            }
        }
        __syncthreads();
        // coalesced copy-out: each thread 32B of one row
        uint4 d0 = *(const uint4*)(&Ash[sp * 72 + pp * 16]);
        uint4 d1 = *(const uint4*)(&Ash[sp * 72 + pp * 16 + 8]);
        *(uint4*)(out_bf + (size_t)(sBase + sp) * 64 + pp * 16) = d0;
        *(uint4*)(out_bf + (size_t)(sBase + sp) * 64 + pp * 16 + 8) = d1;
    } else {
#pragma unroll
        for (int mt = 0; mt < 4; ++mt) {
#pragma unroll
            for (int r = 0; r < 4; ++r) {
                int site = 16 * mt + 4 * quad + r;
                float v = acc[mt][r];
                ssum += v;
                ssq += v * v;
                out_f[(size_t)(sBase + site) * 64 + ch] = v;
            }
        }
    }

    // per-channel stats: reduce across quads (same ch at lane&15), then one atomic per channel
    ssum += __shfl_xor(ssum, 16);
    ssum += __shfl_xor(ssum, 32);
    ssq  += __shfl_xor(ssq, 16);
    ssq  += __shfl_xor(ssq, 32);
    if (lane < 16) {
        atomicAdd(&s_sum[ch], ssum);
        atomicAdd(&s_sq[ch], ssq);
    }
}

// ---------------- BN finalize: a = gamma*rsqrt(var+eps), b = beta - mean*a ----------------
__global__ void finalize_kernel(const float* __restrict__ sum, const float* __restrict__ sq,
                                const float* __restrict__ gamma, const float* __restrict__ beta,
                                float* __restrict__ a, float* __restrict__ b) {
    int c = threadIdx.x;
    const float invn = 1.0f / (float)NSITES;
    float m = sum[c] * invn;
    float v = sq[c] * invn - m * m;
    float s = gamma[c] * rsqrtf(v + EPS_BN);
    a[c] = s;
    b[c] = beta[c] - m * s;
}

// ---------------- residual epilogue: out = relu(a2*h2 + b2 + features) in-place ----------------
__global__ void residual_kernel(float* __restrict__ out, const float* __restrict__ feat,
                                const float* __restrict__ a2, const float* __restrict__ b2,
                                int total4) {
    int stride = gridDim.x * blockDim.x;
    for (int i = blockIdx.x * blockDim.x + threadIdx.x; i < total4; i += stride) {
        float4 h = ((const float4*)out)[i];
        float4 f = ((const float4*)feat)[i];
        int c4 = (i & 15) * 4;
        float4 av = *(const float4*)(a2 + c4);
        float4 bv = *(const float4*)(b2 + c4);
        float4 r;
        r.x = fmaxf(av.x * h.x + bv.x + f.x, 0.f);
        r.y = fmaxf(av.y * h.y + bv.y + f.y, 0.f);
        r.z = fmaxf(av.z * h.z + bv.z + f.z, 0.f);
        r.w = fmaxf(av.w * h.w + bv.w + f.w, 0.f);
        ((float4*)out)[i] = r;
    }
}

extern "C" void kernel_launch(void* const* d_in, const int* in_sizes, int n_in,
                              void* d_out, int out_size, void* d_ws, size_t ws_size,
                              hipStream_t stream) {
    const float* features = (const float*)d_in[0];
    const int* nbr        = (const int*)d_in[1];
    const float* W1       = (const float*)d_in[2];
    const float* gamma1   = (const float*)d_in[3];
    const float* beta1    = (const float*)d_in[4];
    const float* W2       = (const float*)d_in[5];
    const float* gamma2   = (const float*)d_in[6];
    const float* beta2    = (const float*)d_in[7];

    char* ws = (char*)d_ws;
    const size_t NB = (size_t)NSITES * CCH * sizeof(unsigned short);  // 128 MB

    // fbf lives in d_out's first 128 MB (dead once conv2 overwrites d_out with fp32 h2)
    ushort_t* fbf = (ushort_t*)d_out;                 // [N][64] bf16
    ushort_t* h1  = (ushort_t*)ws;                    // [N][64] bf16 (128 MB)
    ushort_t* W1s = (ushort_t*)(ws + NB);             // 147456 B
    ushort_t* W2s = (ushort_t*)(ws + NB + 147456);    // 147456 B
    float* stats  = (float*)(ws + NB + 294912);       // sum1,sq1,sum2,sq2 (4*64 fp32)
    float* ab     = (float*)(ws + NB + 294912 + 1024);// a1,b1,a2,b2

    hipMemsetAsync(stats, 0, 256 * sizeof(float), stream);
    cast_kernel<<<8192, 256, 0, stream>>>(features, fbf, NSITES * CCH / 8);
    swizzle_kernel<<<288, 256, 0, stream>>>(W1, W2, W1s, W2s);

    conv_kernel<false, true><<<NSITES / 64, 256, 0, stream>>>(
        fbf, nbr, W1s, nullptr, nullptr, h1, nullptr, stats + 0, stats + 64);
    finalize_kernel<<<1, 64, 0, stream>>>(stats + 0, stats + 64, gamma1, beta1, ab + 0, ab + 64);

    conv_kernel<true, false><<<NSITES / 64, 256, 0, stream>>>(
        h1, nbr, W2s, ab + 0, ab + 64, nullptr, (float*)d_out, stats + 128, stats + 192);
    finalize_kernel<<<1, 64, 0, stream>>>(stats + 128, stats + 192, gamma2, beta2, ab + 128, ab + 192);

    residual_kernel<<<8192, 256, 0, stream>>>((float*)d_out, features, ab + 128, ab + 192,
                                              NSITES * CCH / 4);
}

// Round 3
// 1081.078 us; speedup vs baseline: 1.2625x; 1.2625x over previous
//
#include <hip/hip_runtime.h>

#define NSITES 1000000
#define CCH 64
#define EPS_BN 1e-5f

typedef __bf16 bf16x8 __attribute__((ext_vector_type(8)));
typedef float f32x4 __attribute__((ext_vector_type(4)));
typedef unsigned short ushort_t;

__device__ __forceinline__ unsigned short f2bf(float x) {
    __bf16 h = (__bf16)x;
    return __builtin_bit_cast(unsigned short, h);
}
__device__ __forceinline__ float bf2f(unsigned short u) {
    return (float)__builtin_bit_cast(__bf16, u);
}

// ---------------- cast features fp32 -> bf16 ----------------
__global__ void cast_kernel(const float* __restrict__ f, ushort_t* __restrict__ o, int total8) {
    int stride = gridDim.x * blockDim.x;
    for (int i = blockIdx.x * blockDim.x + threadIdx.x; i < total8; i += stride) {
        const float4* fp = (const float4*)(f + (size_t)i * 8);
        float4 v0 = fp[0];
        float4 v1 = fp[1];
        uint4 packed;
        ushort_t* up = (ushort_t*)&packed;
        up[0] = f2bf(v0.x); up[1] = f2bf(v0.y); up[2] = f2bf(v0.z); up[3] = f2bf(v0.w);
        up[4] = f2bf(v1.x); up[5] = f2bf(v1.y); up[6] = f2bf(v1.z); up[7] = f2bf(v1.w);
        *(uint4*)(o + (size_t)i * 8) = packed;
    }
}

// ---------------- swizzle W (fp32 [9][64][64]) into B-fragment order bf16 ----------------
// dst index u = (((tap*2+kk)*4 + nt)*64 + lane)*8 + j
// maps to W[tap][k = 32*kk + 8*(lane>>4) + j][n = 16*nt + (lane&15)]
__global__ void swizzle_kernel(const float* __restrict__ W1, const float* __restrict__ W2,
                               ushort_t* __restrict__ W1s, ushort_t* __restrict__ W2s) {
    int t = blockIdx.x * blockDim.x + threadIdx.x;  // 0..73727
    const float* Wg = W1;
    ushort_t* dst = W1s;
    int u = t;
    if (t >= 36864) { Wg = W2; dst = W2s; u = t - 36864; }
    int j = u & 7;
    int lane = (u >> 3) & 63;
    int nt = (u >> 9) & 3;
    int kk = (u >> 11) & 1;
    int tap = u >> 12;
    int k = 32 * kk + 8 * (lane >> 4) + j;
    int n = 16 * nt + (lane & 15);
    dst[u] = f2bf(Wg[tap * 4096 + k * 64 + n]);
}

// ---------------- A-fragment gather: 2 m-tiles x 2 k-frags, direct from global ----------------
__device__ __forceinline__ void gatherA(const ushort_t* __restrict__ fin,
                                        const int (&idxr)[2][9], int t, int quad,
                                        uint4 (&dst)[2][2]) {
#pragma unroll
    for (int mt = 0; mt < 2; ++mt) {
        int id = idxr[mt][t];
        int r = (id < 0) ? NSITES : id;  // row NSITES = zero row (L1-hot)
        const uint4* p = (const uint4*)(fin + ((size_t)r << 6) + (quad << 3));
        dst[mt][0] = p[0];   // k = 0..31 slice (quad*8 + j)
        dst[mt][1] = p[4];   // k = 32..63 slice (+32 ushorts = +4 uint4)
    }
}

// ---------------- conv kernel: barrier-free, wave = 32 sites x 64 ch ----------------
template <bool OUT_BF16>
__global__ __launch_bounds__(256) void conv_kernel(
    const ushort_t* __restrict__ fin,   // [N+1][64] bf16, row N = zeros
    const int* __restrict__ nbr,        // [N][9]
    const ushort_t* __restrict__ Wsw,   // swizzled bf16 W fragments
    ushort_t* __restrict__ out_bf, float* __restrict__ out_f,
    float* __restrict__ s_sum, float* __restrict__ s_sq) {

    __shared__ float bs_sum[64];
    __shared__ float bs_sq[64];

    const int tid  = threadIdx.x;
    const int wv   = tid >> 6;
    const int lane = tid & 63;
    const int quad = lane >> 4;
    const int l15  = lane & 15;
    const int sbase = blockIdx.x * 128 + wv * 32;

    if (tid < 64) { bs_sum[tid] = 0.f; bs_sq[tid] = 0.f; }
    __syncthreads();

    // preload all 18 neighbor indices (tail sites forced invalid)
    int idxr[2][9];
#pragma unroll
    for (int mt = 0; mt < 2; ++mt) {
        int s = sbase + mt * 16 + l15;
        int sc = (s < NSITES) ? s : 0;
        bool sv = (s < NSITES);
#pragma unroll
        for (int t = 0; t < 9; ++t) {
            int id = nbr[(size_t)sc * 9 + t];
            idxr[mt][t] = sv ? id : -1;
        }
    }

    f32x4 acc[2][4];
#pragma unroll
    for (int mt = 0; mt < 2; ++mt)
#pragma unroll
        for (int nt = 0; nt < 4; ++nt) acc[mt][nt] = (f32x4){0.f, 0.f, 0.f, 0.f};

    uint4 abuf[2][2][2];  // [phase][mt][kk]
    gatherA(fin, idxr, 0, quad, abuf[0]);

#pragma unroll
    for (int t = 0; t < 9; ++t) {
        // B fragments FIRST (so the MFMA waitcnt keeps next-tap gathers in flight)
        bf16x8 B[2][4];
#pragma unroll
        for (int kk = 0; kk < 2; ++kk)
#pragma unroll
            for (int nt = 0; nt < 4; ++nt)
                B[kk][nt] = *(const bf16x8*)(Wsw + (size_t)(((t * 2 + kk) * 4 + nt) * 64 + lane) * 8);

        if (t < 8) gatherA(fin, idxr, t + 1, quad, abuf[(t + 1) & 1]);

#pragma unroll
        for (int mt = 0; mt < 2; ++mt) {
            bf16x8 a0 = __builtin_bit_cast(bf16x8, abuf[t & 1][mt][0]);
            bf16x8 a1 = __builtin_bit_cast(bf16x8, abuf[t & 1][mt][1]);
#pragma unroll
            for (int nt = 0; nt < 4; ++nt) {
                acc[mt][nt] = __builtin_amdgcn_mfma_f32_16x16x32_bf16(a0, B[0][nt], acc[mt][nt], 0, 0, 0);
                acc[mt][nt] = __builtin_amdgcn_mfma_f32_16x16x32_bf16(a1, B[1][nt], acc[mt][nt], 0, 0, 0);
            }
        }
    }

    // ---- per-channel stats: C/D layout ch = nt*16 + l15, site = mt*16 + 4*quad + r ----
    float ss[4] = {0.f, 0.f, 0.f, 0.f};
    float sq[4] = {0.f, 0.f, 0.f, 0.f};
#pragma unroll
    for (int mt = 0; mt < 2; ++mt)
#pragma unroll
        for (int nt = 0; nt < 4; ++nt)
#pragma unroll
            for (int r = 0; r < 4; ++r) {
                float v = acc[mt][nt][r];
                ss[nt] += v;
                sq[nt] += v * v;
            }
#pragma unroll
    for (int nt = 0; nt < 4; ++nt) {
        ss[nt] += __shfl_xor(ss[nt], 16);
        ss[nt] += __shfl_xor(ss[nt], 32);
        sq[nt] += __shfl_xor(sq[nt], 16);
        sq[nt] += __shfl_xor(sq[nt], 32);
    }
    if (lane < 16) {
#pragma unroll
        for (int nt = 0; nt < 4; ++nt) {
            atomicAdd(&bs_sum[nt * 16 + l15], ss[nt]);
            atomicAdd(&bs_sq[nt * 16 + l15], sq[nt]);
        }
    }

    // ---- store ----
    if constexpr (OUT_BF16) {
        __shared__ ushort_t tr[4 * 32 * 72];
        ushort_t* w_tr = tr + wv * 32 * 72;
#pragma unroll
        for (int mt = 0; mt < 2; ++mt)
#pragma unroll
            for (int nt = 0; nt < 4; ++nt)
#pragma unroll
                for (int r = 0; r < 4; ++r)
                    w_tr[(mt * 16 + 4 * quad + r) * 72 + nt * 16 + l15] = f2bf(acc[mt][nt][r]);
        // wave-private region: lgkmcnt ordering only, no barrier needed
        int site_s = lane >> 1;
        int half = lane & 1;
        int gs = sbase + site_s;
        if (gs < NSITES) {
#pragma unroll
            for (int c = 0; c < 4; ++c) {
                uint4 d = *(const uint4*)(w_tr + site_s * 72 + half * 32 + c * 8);
                *(uint4*)(out_bf + (size_t)gs * 64 + half * 32 + c * 8) = d;
            }
        }
    } else {
#pragma unroll
        for (int mt = 0; mt < 2; ++mt)
#pragma unroll
            for (int nt = 0; nt < 4; ++nt)
#pragma unroll
                for (int r = 0; r < 4; ++r) {
                    int site = sbase + mt * 16 + 4 * quad + r;
                    if (site < NSITES)
                        out_f[(size_t)site * 64 + nt * 16 + l15] = acc[mt][nt][r];
                }
    }

    __syncthreads();
    if (tid < 64) {
        atomicAdd(&s_sum[tid], bs_sum[tid]);
        atomicAdd(&s_sq[tid], bs_sq[tid]);
    }
}

// ---------------- BN finalize ----------------
__global__ void finalize_kernel(const float* __restrict__ sum, const float* __restrict__ sq,
                                const float* __restrict__ gamma, const float* __restrict__ beta,
                                float* __restrict__ a, float* __restrict__ b) {
    int c = threadIdx.x;
    const float invn = 1.0f / (float)NSITES;
    float m = sum[c] * invn;
    float v = sq[c] * invn - m * m;
    float s = gamma[c] * rsqrtf(v + EPS_BN);
    a[c] = s;
    b[c] = beta[c] - m * s;
}

// ---------------- BN1+ReLU applied once per site, in-place on bf16 h1 ----------------
__global__ void act_kernel(ushort_t* __restrict__ h, const float* __restrict__ a,
                           const float* __restrict__ b, int total8) {
    int stride = gridDim.x * blockDim.x;
    for (int i = blockIdx.x * blockDim.x + threadIdx.x; i < total8; i += stride) {
        int c8 = (i & 7) * 8;
        uint4 v = ((const uint4*)h)[i];
        ushort_t* up = (ushort_t*)&v;
#pragma unroll
        for (int j = 0; j < 8; ++j) {
            float x = bf2f(up[j]);
            up[j] = f2bf(fmaxf(a[c8 + j] * x + b[c8 + j], 0.f));
        }
        ((uint4*)h)[i] = v;
    }
}

// ---------------- residual epilogue: out = relu(a2*h2 + b2 + features) in-place ----------------
__global__ void residual_kernel(float* __restrict__ out, const float* __restrict__ feat,
                                const float* __restrict__ a2, const float* __restrict__ b2,
                                int total4) {
    int stride = gridDim.x * blockDim.x;
    for (int i = blockIdx.x * blockDim.x + threadIdx.x; i < total4; i += stride) {
        float4 h = ((const float4*)out)[i];
        float4 f = ((const float4*)feat)[i];
        int c4 = (i & 15) * 4;
        float4 av = *(const float4*)(a2 + c4);
        float4 bv = *(const float4*)(b2 + c4);
        float4 r;
        r.x = fmaxf(av.x * h.x + bv.x + f.x, 0.f);
        r.y = fmaxf(av.y * h.y + bv.y + f.y, 0.f);
        r.z = fmaxf(av.z * h.z + bv.z + f.z, 0.f);
        r.w = fmaxf(av.w * h.w + bv.w + f.w, 0.f);
        ((float4*)out)[i] = r;
    }
}

extern "C" void kernel_launch(void* const* d_in, const int* in_sizes, int n_in,
                              void* d_out, int out_size, void* d_ws, size_t ws_size,
                              hipStream_t stream) {
    const float* features = (const float*)d_in[0];
    const int* nbr        = (const int*)d_in[1];
    const float* W1       = (const float*)d_in[2];
    const float* gamma1   = (const float*)d_in[3];
    const float* beta1    = (const float*)d_in[4];
    const float* W2       = (const float*)d_in[5];
    const float* gamma2   = (const float*)d_in[6];
    const float* beta2    = (const float*)d_in[7];

    char* ws = (char*)d_ws;
    const size_t NB = (size_t)NSITES * CCH * sizeof(unsigned short);  // 128,000,000 B

    // fbf in d_out's first half (+zero row); dead once conv2 overwrites d_out with fp32 h2
    ushort_t* fbf = (ushort_t*)d_out;                 // [N+1][64] bf16
    ushort_t* h1  = (ushort_t*)ws;                    // [N+1][64] bf16
    size_t off = NB + 512;                            // skip zero row, align
    ushort_t* W1s = (ushort_t*)(ws + off);            // 147456 B
    ushort_t* W2s = (ushort_t*)(ws + off + 147456);   // 147456 B
    float* stats  = (float*)(ws + off + 294912);      // sum1,sq1,sum2,sq2 (4*64 fp32)
    float* ab     = (float*)(ws + off + 294912 + 1024);  // a1,b1,a2,b2

    hipMemsetAsync(stats, 0, 256 * sizeof(float), stream);
    hipMemsetAsync(fbf + (size_t)NSITES * 64, 0, 128, stream);  // zero row for conv1 gathers
    hipMemsetAsync(h1 + (size_t)NSITES * 64, 0, 128, stream);   // zero row for conv2 gathers

    cast_kernel<<<8192, 256, 0, stream>>>(features, fbf, NSITES * CCH / 8);
    swizzle_kernel<<<288, 256, 0, stream>>>(W1, W2, W1s, W2s);

    const int nblk = (NSITES + 127) / 128;  // 7813
    conv_kernel<true><<<nblk, 256, 0, stream>>>(
        fbf, nbr, W1s, h1, nullptr, stats + 0, stats + 64);
    finalize_kernel<<<1, 64, 0, stream>>>(stats + 0, stats + 64, gamma1, beta1, ab + 0, ab + 64);

    act_kernel<<<8192, 256, 0, stream>>>(h1, ab + 0, ab + 64, NSITES * CCH / 8);

    conv_kernel<false><<<nblk, 256, 0, stream>>>(
        h1, nbr, W2s, nullptr, (float*)d_out, stats + 128, stats + 192);
    finalize_kernel<<<1, 64, 0, stream>>>(stats + 128, stats + 192, gamma2, beta2, ab + 128, ab + 192);

    residual_kernel<<<8192, 256, 0, stream>>>((float*)d_out, features, ab + 128, ab + 192,
                                              NSITES * CCH / 4);
}